// Round 13
// baseline (109.343 us; speedup 1.0000x reference)
//
#include <hip/hip_runtime.h>
#include <hip/hip_bf16.h>

typedef __attribute__((ext_vector_type(8))) short short8;
typedef __attribute__((ext_vector_type(4))) float f32x4;
typedef unsigned int u32;

#define LDSW 136  // padded row stride (bf16 elems) = 272 B

// round-to-nearest-even f32 -> bf16
static __device__ __forceinline__ ushort f2bf(float f) {
  unsigned int u = __builtin_bit_cast(unsigned int, f);
  u += 0x7fffu + ((u >> 16) & 1u);
  return (ushort)(u >> 16);
}

// ---------------- kernel 1: pack w1 (f32 row-major) -> bf16 [col][k] with padded stride ----
__global__ __launch_bounds__(256) void pack_w1_kernel(const float* __restrict__ w1,
                                                      ushort* __restrict__ w1p) {
  int tid = blockIdx.x * 256 + threadIdx.x;
  int k = tid >> 7;
  int c = tid & 127;
  w1p[c * LDSW + k] = f2bf(w1[k * 128 + c]);
}

// ---------------- kernel 2: column-sum via global_load_lds (R10 champion version) ----------
__global__ __launch_bounds__(256) void colsum_lds_kernel(const float* __restrict__ x,
                                                         float4* __restrict__ partial4) {
  __shared__ float tile[8192];     // 32 KB: 64 rows x 128 cols
  __shared__ float4 red[8][32];    // 4 KB
  int tid = threadIdx.x;
  int lane = tid & 63;
  int wave = tid >> 6;

  const float* gbase = x + (size_t)blockIdx.x * 8192 + (size_t)(wave * 8) * 256 + lane * 4;
  float* lbase = tile + (wave * 8) * 256;  // wave-uniform
#pragma unroll
  for (int i = 0; i < 8; ++i) {
    __builtin_amdgcn_global_load_lds(
        (const __attribute__((address_space(1))) u32*)(gbase + i * 256),
        (__attribute__((address_space(3))) u32*)(lbase + i * 256), 16, 0, 0);
  }
  __syncthreads();  // vmcnt(0) drain + barrier: tile complete

  int c4 = tid & 31;
  int rg = tid >> 5;
  const float4* tile4 = reinterpret_cast<const float4*>(tile);
  float4 acc = {0.f, 0.f, 0.f, 0.f};
#pragma unroll
  for (int k = 0; k < 8; ++k) {
    float4 v = tile4[(rg + 8 * k) * 32 + c4];  // wave reads contiguous 1KB: conflict-free
    acc.x += v.x; acc.y += v.y; acc.z += v.z; acc.w += v.w;
  }
  red[rg][c4] = acc;
  __syncthreads();
  if (tid < 32) {
    float4 s = red[0][tid];
#pragma unroll
    for (int g = 1; g < 8; ++g) {
      float4 v = red[g][tid];
      s.x += v.x; s.y += v.y; s.z += v.z; s.w += v.w;
    }
    partial4[(size_t)blockIdx.x * 32 + tid] = s;
  }
}

// ---------------- kernel 3: reduce partial[3125][128] -> partial2[128][128] ----------------
__global__ __launch_bounds__(256) void reduce_kernel(const float* __restrict__ partial,
                                                     float* __restrict__ partial2,
                                                     int nb) {
  int tid = threadIdx.x;
  int j = tid & 127;
  int orow = blockIdx.x * 2 + (tid >> 7);  // 64 blocks -> orow 0..127
  float s = 0.f;
  for (int r = orow; r < nb; r += 128) s += partial[(size_t)r * 128 + j];
  partial2[orow * 128 + j] = s;
}

// ---------------- kernel 4: t = (pooled @ w2)/n + bias  (1 block x 1024 thr) ---------------
__global__ __launch_bounds__(1024) void transmit_kernel(const float* __restrict__ partial,
                                                        const float* __restrict__ w2,
                                                        const float* __restrict__ bias,
                                                        float* __restrict__ t, int n,
                                                        int nblocks) {
  __shared__ float red[8][128];
  __shared__ float pooled[128];
  int tid = threadIdx.x;
  int j = tid & 127;
  int g = tid >> 7;

  float s = 0.f;
  for (int b = g; b < nblocks; b += 8) s += partial[b * 128 + j];
  red[g][j] = s;
  __syncthreads();
  if (tid < 128) {
    float p = 0.f;
#pragma unroll
    for (int gg = 0; gg < 8; ++gg) p += red[gg][j];
    pooled[j] = p;
  }
  __syncthreads();

  float acc = 0.f;
#pragma unroll
  for (int ii = 0; ii < 16; ++ii) {
    int i = g * 16 + ii;
    acc += pooled[i] * w2[i * 128 + j];
  }
  __syncthreads();
  red[g][j] = acc;
  __syncthreads();
  if (tid < 128) {
    float a = 0.f;
#pragma unroll
    for (int gg = 0; gg < 8; ++gg) a += red[gg][j];
    t[j] = a / (float)n + bias[j];
  }
}

// ---------------- kernel 5: out = x @ w1 + t  (bf16 MFMA; x L3-warm from colsum) -----------
// R13 PROBE: this kernel is dispatched TWICE (idempotent — identical bytes both times).
// total_R13 - total_R10 = gemm's true graph-replay cost, in natural cache state.
__global__ __launch_bounds__(256) void gemm_kernel(const float* __restrict__ x,
                                                   const ushort* __restrict__ w1p,
                                                   const float* __restrict__ tvec,
                                                   float* __restrict__ out) {
  __shared__ ushort w1t[128 * LDSW];
  __shared__ float t_lds[128];
  int tid = threadIdx.x;

  {
    const ulonglong2* src = reinterpret_cast<const ulonglong2*>(w1p);
    ulonglong2* dst = reinterpret_cast<ulonglong2*>(w1t);
#pragma unroll
    for (int i = 0; i < (128 * LDSW * 2) / 16 / 256 + 1; ++i) {
      int idx = tid + i * 256;
      if (idx < (128 * LDSW * 2) / 16) dst[idx] = src[idx];
    }
  }
  if (tid < 128) t_lds[tid] = tvec[tid];
  __syncthreads();

  int lane = tid & 63;
  int wave = tid >> 6;
  int c = lane & 15;    // A row-in-tile / B col / D col
  int kg = lane >> 4;   // k-group 0..3
  int rbase = blockIdx.x * 64 + wave * 16;
  const float* xrow = x + (size_t)(rbase + c) * 128;

  f32x4 acc[8];
#pragma unroll
  for (int nb = 0; nb < 8; ++nb) acc[nb] = (f32x4){0.f, 0.f, 0.f, 0.f};

#pragma unroll
  for (int kb = 0; kb < 4; ++kb) {
    int k0 = kb * 32 + kg * 8;
    float4 a0 = *reinterpret_cast<const float4*>(xrow + k0);
    float4 a1 = *reinterpret_cast<const float4*>(xrow + k0 + 4);
    short8 afrag;
    afrag[0] = (short)f2bf(a0.x);
    afrag[1] = (short)f2bf(a0.y);
    afrag[2] = (short)f2bf(a0.z);
    afrag[3] = (short)f2bf(a0.w);
    afrag[4] = (short)f2bf(a1.x);
    afrag[5] = (short)f2bf(a1.y);
    afrag[6] = (short)f2bf(a1.z);
    afrag[7] = (short)f2bf(a1.w);
#pragma unroll
    for (int nb = 0; nb < 8; ++nb) {
      short8 bfrag = *reinterpret_cast<const short8*>(&w1t[(nb * 16 + c) * LDSW + k0]);
      acc[nb] = __builtin_amdgcn_mfma_f32_16x16x32_bf16(afrag, bfrag, acc[nb], 0, 0, 0);
    }
  }

  // D layout (m89-verified): col = lane&15, row = (lane>>4)*4 + reg
#pragma unroll
  for (int nb = 0; nb < 8; ++nb) {
    int col = nb * 16 + c;
    float tv = t_lds[col];
#pragma unroll
    for (int i = 0; i < 4; ++i) {
      out[(size_t)(rbase + kg * 4 + i) * 128 + col] = acc[nb][i] + tv;
    }
  }
}

extern "C" void kernel_launch(void* const* d_in, const int* in_sizes, int n_in,
                              void* d_out, int out_size, void* d_ws, size_t ws_size,
                              hipStream_t stream) {
  const float* x = (const float*)d_in[0];
  const float* w1 = (const float*)d_in[1];
  const float* w2 = (const float*)d_in[2];
  const float* bias = (const float*)d_in[3];
  float* out = (float*)d_out;
  int n = in_sizes[0] / 128;  // 200000
  int nb = n / 64;            // 3125 tile blocks

  char* ws = (char*)d_ws;
  float* t = (float*)ws;                     // 512 B
  ushort* w1p = (ushort*)(ws + 512);         // 34,816 B -> ends 35,328
  float* partial = (float*)(ws + 35328);     // 3125*128*4 = 1,600,000 B -> ends 1,635,328
  float* partial2 = (float*)(ws + 1635328);  // 128*128*4 = 65,536 B

  hipLaunchKernelGGL(pack_w1_kernel, dim3(64), dim3(256), 0, stream, w1, w1p);
  hipLaunchKernelGGL(colsum_lds_kernel, dim3(nb), dim3(256), 0, stream,
                     x, (float4*)partial);
  hipLaunchKernelGGL(reduce_kernel, dim3(64), dim3(256), 0, stream, partial, partial2, nb);
  hipLaunchKernelGGL(transmit_kernel, dim3(1), dim3(1024), 0, stream,
                     partial2, w2, bias, t, n, 128);
  hipLaunchKernelGGL(gemm_kernel, dim3(nb), dim3(256), 0, stream, x, w1p, t, out);
  // PROBE dispatch: identical, idempotent. Its marginal cost = gemm's true replay time.
  hipLaunchKernelGGL(gemm_kernel, dim3(nb), dim3(256), 0, stream, x, w1p, t, out);
}

// Round 14
// 76.002 us; speedup vs baseline: 1.4387x; 1.4387x over previous
//
#include <hip/hip_runtime.h>
#include <hip/hip_bf16.h>

typedef __attribute__((ext_vector_type(8))) short short8;
typedef __attribute__((ext_vector_type(4))) float f32x4;
typedef unsigned int u32;

#define LDSW 136  // padded row stride (bf16 elems) = 272 B

// round-to-nearest-even f32 -> bf16
static __device__ __forceinline__ ushort f2bf(float f) {
  unsigned int u = __builtin_bit_cast(unsigned int, f);
  u += 0x7fffu + ((u >> 16) & 1u);
  return (ushort)(u >> 16);
}

static __device__ __forceinline__ ushort4 pack4(float4 v) {
  ushort4 r;
  r.x = f2bf(v.x); r.y = f2bf(v.y); r.z = f2bf(v.z); r.w = f2bf(v.w);
  return r;
}

// ---------------- kernel 1: pack w1 (f32 row-major) -> bf16 [col][k] with padded stride ----
__global__ __launch_bounds__(256) void pack_w1_kernel(const float* __restrict__ w1,
                                                      ushort* __restrict__ w1p) {
  int tid = blockIdx.x * 256 + threadIdx.x;
  int k = tid >> 7;
  int c = tid & 127;
  w1p[c * LDSW + k] = f2bf(w1[k * 128 + c]);
}

// ---------------- kernel 2: column-sum via global_load_lds + bf16 stash --------------------
// R13 probe decomposition: colsum 31us (at the 3.3 TB/s empirical read ceiling), gemm 34.4us
// (95% of copy ceiling — its x re-read only ~half-hits L3 because out's dirty fills evict
// not-yet-read x). Fix: stash bf16(x) here (51MB, written once at 7 TB/s store rate) so the
// gemm reads HALF the bytes — small enough to survive in L3 alongside out (153MB < 256MB).
// Numerically identical to before: same f2bf the gemm applied, just moved earlier.
__global__ __launch_bounds__(256) void colsum_lds_kernel(const float* __restrict__ x,
                                                         ushort4* __restrict__ stash4,
                                                         float4* __restrict__ partial4) {
  __shared__ float tile[8192];     // 32 KB: 64 rows x 128 cols
  __shared__ float4 red[8][32];    // 4 KB
  int tid = threadIdx.x;
  int lane = tid & 63;
  int wave = tid >> 6;

  const float* gbase = x + (size_t)blockIdx.x * 8192 + (size_t)(wave * 8) * 256 + lane * 4;
  float* lbase = tile + (wave * 8) * 256;  // wave-uniform
#pragma unroll
  for (int i = 0; i < 8; ++i) {
    __builtin_amdgcn_global_load_lds(
        (const __attribute__((address_space(1))) u32*)(gbase + i * 256),
        (__attribute__((address_space(3))) u32*)(lbase + i * 256), 16, 0, 0);
  }
  __syncthreads();  // vmcnt(0) drain + barrier: tile complete

  int c4 = tid & 31;
  int rg = tid >> 5;
  const float4* tile4 = reinterpret_cast<const float4*>(tile);
  ushort4* sb = stash4 + (size_t)blockIdx.x * 2048;  // 64 rows x 32 ushort4
  float4 acc = {0.f, 0.f, 0.f, 0.f};
#pragma unroll
  for (int k = 0; k < 8; ++k) {
    int ridx = (rg + 8 * k) * 32 + c4;
    float4 v = tile4[ridx];  // wave reads contiguous 1KB: conflict-free
    sb[ridx] = pack4(v);     // coalesced 8B/lane bf16 stash write
    acc.x += v.x; acc.y += v.y; acc.z += v.z; acc.w += v.w;
  }
  red[rg][c4] = acc;
  __syncthreads();
  if (tid < 32) {
    float4 s = red[0][tid];
#pragma unroll
    for (int g = 1; g < 8; ++g) {
      float4 v = red[g][tid];
      s.x += v.x; s.y += v.y; s.z += v.z; s.w += v.w;
    }
    partial4[(size_t)blockIdx.x * 32 + tid] = s;
  }
}

// ---------------- kernel 3: reduce partial[3125][128] -> partial2[128][128] ----------------
__global__ __launch_bounds__(256) void reduce_kernel(const float* __restrict__ partial,
                                                     float* __restrict__ partial2,
                                                     int nb) {
  int tid = threadIdx.x;
  int j = tid & 127;
  int orow = blockIdx.x * 2 + (tid >> 7);  // 64 blocks -> orow 0..127
  float s = 0.f;
  for (int r = orow; r < nb; r += 128) s += partial[(size_t)r * 128 + j];
  partial2[orow * 128 + j] = s;
}

// ---------------- kernel 4: t = (pooled @ w2)/n + bias  (1 block x 1024 thr) ---------------
__global__ __launch_bounds__(1024) void transmit_kernel(const float* __restrict__ partial,
                                                        const float* __restrict__ w2,
                                                        const float* __restrict__ bias,
                                                        float* __restrict__ t, int n,
                                                        int nblocks) {
  __shared__ float red[8][128];
  __shared__ float pooled[128];
  int tid = threadIdx.x;
  int j = tid & 127;
  int g = tid >> 7;

  float s = 0.f;
  for (int b = g; b < nblocks; b += 8) s += partial[b * 128 + j];
  red[g][j] = s;
  __syncthreads();
  if (tid < 128) {
    float p = 0.f;
#pragma unroll
    for (int gg = 0; gg < 8; ++gg) p += red[gg][j];
    pooled[j] = p;
  }
  __syncthreads();

  float acc = 0.f;
#pragma unroll
  for (int ii = 0; ii < 16; ++ii) {
    int i = g * 16 + ii;
    acc += pooled[i] * w2[i * 128 + j];
  }
  __syncthreads();
  red[g][j] = acc;
  __syncthreads();
  if (tid < 128) {
    float a = 0.f;
#pragma unroll
    for (int gg = 0; gg < 8; ++gg) a += red[gg][j];
    t[j] = a / (float)n + bias[j];
  }
}

// ---------------- kernel 5: out = stash @ w1 + t  (bf16 MFMA; half-size L3-resident read) --
__global__ __launch_bounds__(256) void gemm_kernel(const ushort* __restrict__ xb,
                                                   const ushort* __restrict__ w1p,
                                                   const float* __restrict__ tvec,
                                                   float* __restrict__ out) {
  __shared__ ushort w1t[128 * LDSW];
  __shared__ float t_lds[128];
  int tid = threadIdx.x;

  {
    const ulonglong2* src = reinterpret_cast<const ulonglong2*>(w1p);
    ulonglong2* dst = reinterpret_cast<ulonglong2*>(w1t);
#pragma unroll
    for (int i = 0; i < (128 * LDSW * 2) / 16 / 256 + 1; ++i) {
      int idx = tid + i * 256;
      if (idx < (128 * LDSW * 2) / 16) dst[idx] = src[idx];
    }
  }
  if (tid < 128) t_lds[tid] = tvec[tid];
  __syncthreads();

  int lane = tid & 63;
  int wave = tid >> 6;
  int c = lane & 15;    // A row-in-tile / B col / D col
  int kg = lane >> 4;   // k-group 0..3
  int rbase = blockIdx.x * 64 + wave * 16;
  const ushort* xrow = xb + (size_t)(rbase + c) * 128;

  f32x4 acc[8];
#pragma unroll
  for (int nb = 0; nb < 8; ++nb) acc[nb] = (f32x4){0.f, 0.f, 0.f, 0.f};

#pragma unroll
  for (int kb = 0; kb < 4; ++kb) {
    int k0 = kb * 32 + kg * 8;
    short8 afrag = *reinterpret_cast<const short8*>(xrow + k0);  // 16B direct bf16 load
#pragma unroll
    for (int nb = 0; nb < 8; ++nb) {
      short8 bfrag = *reinterpret_cast<const short8*>(&w1t[(nb * 16 + c) * LDSW + k0]);
      acc[nb] = __builtin_amdgcn_mfma_f32_16x16x32_bf16(afrag, bfrag, acc[nb], 0, 0, 0);
    }
  }

  // D layout (m89-verified): col = lane&15, row = (lane>>4)*4 + reg
#pragma unroll
  for (int nb = 0; nb < 8; ++nb) {
    int col = nb * 16 + c;
    float tv = t_lds[col];
#pragma unroll
    for (int i = 0; i < 4; ++i) {
      out[(size_t)(rbase + kg * 4 + i) * 128 + col] = acc[nb][i] + tv;
    }
  }
}

extern "C" void kernel_launch(void* const* d_in, const int* in_sizes, int n_in,
                              void* d_out, int out_size, void* d_ws, size_t ws_size,
                              hipStream_t stream) {
  const float* x = (const float*)d_in[0];
  const float* w1 = (const float*)d_in[1];
  const float* w2 = (const float*)d_in[2];
  const float* bias = (const float*)d_in[3];
  float* out = (float*)d_out;
  int n = in_sizes[0] / 128;  // 200000
  int nb = n / 64;            // 3125 tile blocks

  char* ws = (char*)d_ws;
  float* t = (float*)ws;                     // 512 B
  ushort* w1p = (ushort*)(ws + 512);         // 34,816 B -> ends 35,328
  float* partial = (float*)(ws + 35328);     // 3125*128*4 = 1,600,000 B -> ends 1,635,328
  float* partial2 = (float*)(ws + 1635328);  // 65,536 B -> ends 1,700,864
  ushort* stash = (ushort*)(ws + 1700864);   // 25.6M bf16 = 51,200,000 B

  hipLaunchKernelGGL(pack_w1_kernel, dim3(64), dim3(256), 0, stream, w1, w1p);
  hipLaunchKernelGGL(colsum_lds_kernel, dim3(nb), dim3(256), 0, stream,
                     x, (ushort4*)stash, (float4*)partial);
  hipLaunchKernelGGL(reduce_kernel, dim3(64), dim3(256), 0, stream, partial, partial2, nb);
  hipLaunchKernelGGL(transmit_kernel, dim3(1), dim3(1024), 0, stream,
                     partial2, w2, bias, t, n, 128);
  hipLaunchKernelGGL(gemm_kernel, dim3(nb), dim3(256), 0, stream, stash, w1p, t, out);
}